// Round 2
// baseline (438.855 us; speedup 1.0000x reference)
//
#include <hip/hip_runtime.h>
#include <math.h>

#define BATCH 128
#define NANCH 8400
#define NMSK  300
#define KPT   17
#define OUTC  56   // 4 box + 1 score + 34 kpt + 17 vis

// ---------------------------------------------------------------------------
// Kernel 1: fused score + EXACT f32 top-300 per batch (np-f32 semantics).
// Score replicates numpy f32: s = 1.0f/(1.0f + exp_f32(-x)), product in f32,
// where exp_f32 is the correctly-rounded f32 exp (via f64 exp, matches
// SVML-HA np.exp to <1ulp). Selection: exact f32 bits, ties by lower index.
// One block per batch, 256 threads.
// ---------------------------------------------------------------------------
__global__ __launch_bounds__(256) void topk_kernel(
    const float* __restrict__ cls, const float* __restrict__ obj,
    int* __restrict__ top_idx, float* __restrict__ top_val)
{
    const int b = blockIdx.x;
    const int tid = threadIdx.x;

    __shared__ unsigned int sc[NANCH];          // f32 score bits (positive -> bit order == float order)
    __shared__ unsigned int hist[256];
    __shared__ unsigned int suf[256];
    __shared__ unsigned int sh_prefix, sh_k, sh_cnt;
    __shared__ unsigned long long ckey[1024];   // packed (bits<<32)|(~idx)

    const float* c = cls + (size_t)b * NANCH;
    const float* o = obj + (size_t)b * NANCH;

    // Phase A: f32 scores, np-exact op order
    for (int i = tid; i < NANCH; i += 256) {
        float ea = (float)exp(-(double)c[i]);   // correctly-rounded f32 exp
        float eo = (float)exp(-(double)o[i]);
        float sa = 1.0f / (1.0f + ea);
        float so = 1.0f / (1.0f + eo);
        sc[i] = __float_as_uint(sa * so);
    }
    if (tid == 0) { sh_prefix = 0u; sh_k = NMSK; sh_cnt = 0u; }
    __syncthreads();

    // Phase B: radix-select the exact 300th-largest f32 bit pattern
    for (int r = 3; r >= 0; --r) {
        hist[tid] = 0u;
        __syncthreads();
        unsigned int pfx  = sh_prefix;
        unsigned int kcur = sh_k;
        for (int i = tid; i < NANCH; i += 256) {
            unsigned int key = sc[i];
            bool match = (r == 3) || ((key >> ((r + 1) * 8)) == pfx);
            if (match) atomicAdd(&hist[(key >> (r * 8)) & 0xFFu], 1u);
        }
        __syncthreads();
        // suffix sum: suf[d] = #elements with digit >= d
        suf[tid] = hist[tid];
        __syncthreads();
        for (int d = 1; d < 256; d <<= 1) {
            unsigned int v   = suf[tid];
            unsigned int add = (tid + d < 256) ? suf[tid + d] : 0u;
            __syncthreads();
            suf[tid] = v + add;
            __syncthreads();
        }
        unsigned int ge     = suf[tid];
        unsigned int genext = (tid < 255) ? suf[tid + 1] : 0u;
        if (ge >= kcur && genext < kcur) {       // exactly one thread
            sh_prefix = (pfx << 8) | (unsigned int)tid;
            sh_k      = kcur - genext;
        }
        __syncthreads();
    }

    // Phase C: compact all candidates with bits >= pivot (exact; count >= 300)
    unsigned int pivot_bits = sh_prefix;
    for (int i = tid; i < 1024; i += 256) ckey[i] = 0ull;
    __syncthreads();
    for (int i = tid; i < NANCH; i += 256) {
        unsigned int key = sc[i];
        if (key >= pivot_bits) {
            unsigned int p = atomicAdd(&sh_cnt, 1u);
            if (p < 1024u)
                ckey[p] = ((unsigned long long)key << 32)
                        | (unsigned long long)(0xFFFFFFFFu - (unsigned int)i);
        }
    }
    __syncthreads();

    // Phase D: bitonic sort 1024 slots descending; packed key gives
    // (score desc, index asc) — identical to lax.top_k stable ordering.
    for (int sz = 2; sz <= 1024; sz <<= 1) {
        for (int st = sz >> 1; st > 0; st >>= 1) {
            for (int t = tid; t < 1024; t += 256) {
                int ixj = t ^ st;
                if (ixj > t) {
                    unsigned long long ka = ckey[t], kb = ckey[ixj];
                    bool up = ((t & sz) == 0);
                    bool dosw = up ? (kb > ka) : (ka > kb);
                    if (dosw) { ckey[t] = kb; ckey[ixj] = ka; }
                }
            }
            __syncthreads();
        }
    }

    for (int t = tid; t < NMSK; t += 256) {
        unsigned long long k = ckey[t];
        top_idx[b * NMSK + t] = (int)(0xFFFFFFFFu - (unsigned int)(k & 0xFFFFFFFFull));
        top_val[b * NMSK + t] = __uint_as_float((unsigned int)(k >> 32));
    }
}

// ---------------------------------------------------------------------------
// Kernel 2: decode selected boxes, greedy NMS (bitmask), write [300][56] rows.
// One block per batch, 256 threads.
// ---------------------------------------------------------------------------
__global__ __launch_bounds__(256) void nms_out_kernel(
    const float* __restrict__ bbox, const float* __restrict__ kofs,
    const float* __restrict__ kvis, const int* __restrict__ top_idx,
    const float* __restrict__ top_val, float* __restrict__ out)
{
    const int b = blockIdx.x;
    const int tid = threadIdx.x;

    __shared__ float bx1[NMSK], by1[NMSK], bx2[NMSK], by2[NMSK], area[NMSK];
    __shared__ float ppx[NMSK], ppy[NMSK], pst[NMSK], sval[NMSK];
    __shared__ int   sidx[NMSK];
    __shared__ unsigned long long sup[NMSK][5];
    __shared__ unsigned long long keepw[5];

    // decode boxes for the 300 selected anchors
    for (int j = tid; j < NMSK; j += 256) {
        int i = top_idx[b * NMSK + j];
        sidx[j] = i;
        sval[j] = top_val[b * NMSK + j];
        float stride; int row, col;
        if (i < 6400)      { stride = 8.0f;  row = i / 80;              col = i - row * 80; }
        else if (i < 8000) { int ii = i - 6400; stride = 16.0f; row = ii / 40; col = ii - row * 40; }
        else               { int ii = i - 8000; stride = 32.0f; row = ii / 20; col = ii - row * 20; }
        float cx = ((float)col + 0.5f) * stride;
        float cy = ((float)row + 0.5f) * stride;
        ppx[j] = cx; ppy[j] = cy; pst[j] = stride;
        const float* bp = bbox + ((size_t)b * NANCH + (size_t)i) * 4;
        float x = bp[0] * stride + cx;
        float y = bp[1] * stride + cy;
        float w = expf(bp[2]) * stride;
        float h = expf(bp[3]) * stride;
        float x1 = x - 0.5f * w, y1 = y - 0.5f * h;
        float x2 = x + 0.5f * w, y2 = y + 0.5f * h;
        bx1[j] = x1; by1[j] = y1; bx2[j] = x2; by2[j] = y2;
        area[j] = fmaxf(x2 - x1, 0.0f) * fmaxf(y2 - y1, 0.0f);
    }
    __syncthreads();

    // suppression bitmask: row i, bits j>i with IoU > 0.65
    for (int i = tid; i < NMSK; i += 256) {
        unsigned long long m0 = 0, m1 = 0, m2 = 0, m3 = 0, m4 = 0;
        float ax1 = bx1[i], ay1 = by1[i], ax2 = bx2[i], ay2 = by2[i], aa = area[i];
        for (int j = i + 1; j < NMSK; ++j) {
            float lx = fmaxf(ax1, bx1[j]);
            float ly = fmaxf(ay1, by1[j]);
            float rx = fminf(ax2, bx2[j]);
            float ry = fminf(ay2, by2[j]);
            float iw = fmaxf(rx - lx, 0.0f);
            float ih = fmaxf(ry - ly, 0.0f);
            float inter = iw * ih;
            float iou = inter / (aa + area[j] - inter + 1e-7f);
            if (iou > 0.65f) {
                unsigned long long bit = 1ull << (j & 63);
                switch (j >> 6) {
                    case 0: m0 |= bit; break;
                    case 1: m1 |= bit; break;
                    case 2: m2 |= bit; break;
                    case 3: m3 |= bit; break;
                    default: m4 |= bit; break;
                }
            }
        }
        sup[i][0] = m0; sup[i][1] = m1; sup[i][2] = m2; sup[i][3] = m3; sup[i][4] = m4;
    }
    __syncthreads();

    // greedy scan: one wave; lanes 0..4 own the 5 keep words
    if (tid < 64) {
        unsigned long long kw;
        if (tid < 4)       kw = ~0ull;
        else if (tid == 4) kw = (1ull << (NMSK - 256)) - 1ull;  // bits 0..43
        else               kw = 0ull;
        for (int i = 0; i < NMSK; ++i) {
            unsigned int lo = (unsigned int)kw;
            unsigned int hi = (unsigned int)(kw >> 32);
            lo = (unsigned int)__shfl((int)lo, i >> 6, 64);
            hi = (unsigned int)__shfl((int)hi, i >> 6, 64);
            unsigned long long ow = ((unsigned long long)hi << 32) | lo;
            if ((ow >> (i & 63)) & 1ull) {
                if (tid < 5) kw &= ~sup[i][tid];
            }
        }
        if (tid < 5) keepw[tid] = kw;
    }
    __syncthreads();

    // write output rows: [x1 y1 x2 y2 | score | 34 kpt | 17 vis]
    const float* kof = kofs + (size_t)b * NANCH * (KPT * 2);
    const float* kvi = kvis + (size_t)b * NANCH * KPT;
    float* ob = out + (size_t)b * NMSK * OUTC;
    for (int t = tid; t < NMSK * OUTC; t += 256) {
        int j  = t / OUTC;
        int ci = t - j * OUTC;
        float v;
        if (ci == 0)      v = bx1[j];
        else if (ci == 1) v = by1[j];
        else if (ci == 2) v = bx2[j];
        else if (ci == 3) v = by2[j];
        else if (ci == 4) {
            bool kp = (keepw[j >> 6] >> (j & 63)) & 1ull;
            v = kp ? sval[j] : 0.0f;
        } else if (ci < 39) {
            int kk = (ci - 5) >> 1;
            int xy = (ci - 5) & 1;
            float off = kof[((size_t)sidx[j] * KPT + kk) * 2 + xy];
            v = off * pst[j] + ((xy == 0) ? ppx[j] : ppy[j]);
        } else {
            int kk = ci - 39;
            v = 1.0f / (1.0f + expf(-kvi[(size_t)sidx[j] * KPT + kk]));
        }
        ob[t] = v;
    }
}

// ---------------------------------------------------------------------------
extern "C" void kernel_launch(void* const* d_in, const int* in_sizes, int n_in,
                              void* d_out, int out_size, void* d_ws, size_t ws_size,
                              hipStream_t stream) {
    const float* cls  = (const float*)d_in[0];  // [B,N,1]
    const float* bbox = (const float*)d_in[1];  // [B,N,4]
    const float* obj  = (const float*)d_in[2];  // [B,N]
    const float* kofs = (const float*)d_in[3];  // [B,N,17,2]
    const float* kvis = (const float*)d_in[4];  // [B,N,17]

    int*   top_idx = (int*)d_ws;                                   // [B,300]
    float* top_val = (float*)((char*)d_ws + (size_t)BATCH * NMSK * sizeof(int)); // [B,300]
    float* out = (float*)d_out;                                    // [B,300,56]

    topk_kernel<<<BATCH, 256, 0, stream>>>(cls, obj, top_idx, top_val);
    nms_out_kernel<<<BATCH, 256, 0, stream>>>(bbox, kofs, kvis, top_idx, top_val, out);
}

// Round 3
// 349.347 us; speedup vs baseline: 1.2562x; 1.2562x over previous
//
#include <hip/hip_runtime.h>
#include <math.h>

#define BATCH 128
#define NANCH 8400
#define NMSK  300
#define KPT   17
#define OUTC  56   // 4 box + 1 score + 34 kpt + 17 vis
#define CAND  768  // candidate slots (>=300 + tie margin)
#define NBLKE 7650 // BATCH*NMSK*51/256 elementwise blocks in fused kernel

__device__ __forceinline__ void prior_of(int i, float& stride, float& cx, float& cy) {
    int row, col;
    if (i < 6400)      { stride = 8.0f;  row = i / 80;              col = i - row * 80; }
    else if (i < 8000) { int ii = i - 6400; stride = 16.0f; row = ii / 40; col = ii - row * 40; }
    else               { int ii = i - 8000; stride = 32.0f; row = ii / 20; col = ii - row * 20; }
    cx = ((float)col + 0.5f) * stride;
    cy = ((float)row + 0.5f) * stride;
}

// ---------------------------------------------------------------------------
// K1: all B*N fused scores (np-f32-exact) -> sc bits. Massively parallel.
// ---------------------------------------------------------------------------
__global__ __launch_bounds__(256) void scores_kernel(
    const float* __restrict__ cls, const float* __restrict__ obj,
    unsigned int* __restrict__ sc)
{
    int i = blockIdx.x * 256 + threadIdx.x;
    if (i < BATCH * NANCH) {
        float ea = (float)exp(-(double)cls[i]);   // correctly-rounded f32 exp == np.exp
        float eo = (float)exp(-(double)obj[i]);
        float sa = 1.0f / (1.0f + ea);
        float so = 1.0f / (1.0f + eo);
        sc[i] = __float_as_uint(sa * so);
    }
}

// ---------------------------------------------------------------------------
// K2: exact f32 top-300 per batch. Radix-select pivot + rank-based ordering.
// has_sc=0 fallback recomputes scores in-kernel (if ws too small for K1).
// ---------------------------------------------------------------------------
__global__ __launch_bounds__(256) void topk_kernel(
    const float* __restrict__ cls, const float* __restrict__ obj,
    const unsigned int* __restrict__ sc_g, int has_sc,
    int* __restrict__ top_idx, float* __restrict__ top_val)
{
    const int b = blockIdx.x;
    const int tid = threadIdx.x;

    __shared__ unsigned int sc[NANCH];
    __shared__ unsigned int hist[256];
    __shared__ unsigned int suf[256];
    __shared__ unsigned int sh_prefix, sh_k, sh_cnt;
    __shared__ unsigned long long ckey[CAND];   // packed (bits<<32)|(~idx)

    if (has_sc) {
        const unsigned int* s = sc_g + (size_t)b * NANCH;
        for (int i = tid; i < NANCH; i += 256) sc[i] = s[i];
    } else {
        const float* c = cls + (size_t)b * NANCH;
        const float* o = obj + (size_t)b * NANCH;
        for (int i = tid; i < NANCH; i += 256) {
            float ea = (float)exp(-(double)c[i]);
            float eo = (float)exp(-(double)o[i]);
            sc[i] = __float_as_uint((1.0f / (1.0f + ea)) * (1.0f / (1.0f + eo)));
        }
    }
    if (tid == 0) { sh_prefix = 0u; sh_k = NMSK; sh_cnt = 0u; }
    __syncthreads();

    // radix-select exact 300th-largest f32 bit pattern (4 x 8-bit rounds)
    for (int r = 3; r >= 0; --r) {
        hist[tid] = 0u;
        __syncthreads();
        unsigned int pfx  = sh_prefix;
        unsigned int kcur = sh_k;
        for (int i = tid; i < NANCH; i += 256) {
            unsigned int key = sc[i];
            bool match = (r == 3) || ((key >> ((r + 1) * 8)) == pfx);
            if (match) atomicAdd(&hist[(key >> (r * 8)) & 0xFFu], 1u);
        }
        __syncthreads();
        suf[tid] = hist[tid];
        __syncthreads();
        for (int d = 1; d < 256; d <<= 1) {
            unsigned int v   = suf[tid];
            unsigned int add = (tid + d < 256) ? suf[tid + d] : 0u;
            __syncthreads();
            suf[tid] = v + add;
            __syncthreads();
        }
        unsigned int ge     = suf[tid];
        unsigned int genext = (tid < 255) ? suf[tid + 1] : 0u;
        if (ge >= kcur && genext < kcur) {       // exactly one thread
            sh_prefix = (pfx << 8) | (unsigned int)tid;
            sh_k      = kcur - genext;
        }
        __syncthreads();
    }

    // compact all keys >= pivot (count == 300 when values distinct)
    unsigned int pivot_bits = sh_prefix;
    for (int i = tid; i < NANCH; i += 256) {
        unsigned int key = sc[i];
        if (key >= pivot_bits) {
            unsigned int p = atomicAdd(&sh_cnt, 1u);
            if (p < CAND)
                ckey[p] = ((unsigned long long)key << 32)
                        | (unsigned long long)(0xFFFFFFFFu - (unsigned int)i);
        }
    }
    __syncthreads();
    unsigned int M = sh_cnt; if (M > CAND) M = CAND;

    // rank-based ordering: rank = #keys strictly greater (keys are distinct
    // since idx is packed). Gives (score desc, idx asc) == lax.top_k order.
    for (unsigned int j = tid; j < M; j += 256) {
        unsigned long long mine = ckey[j];
        int rank = 0;
        for (unsigned int t2 = 0; t2 < M; ++t2) rank += (ckey[t2] > mine) ? 1 : 0;
        if (rank < NMSK) {
            top_idx[b * NMSK + rank] = (int)(0xFFFFFFFFu - (unsigned int)(mine & 0xFFFFFFFFull));
            top_val[b * NMSK + rank] = __uint_as_float((unsigned int)(mine >> 32));
        }
    }
}

// ---------------------------------------------------------------------------
// K3 (fused): blocks [0,NBLKE) stream kpt/vis output columns (cols 5..55);
// blocks [NBLKE, NBLKE+BATCH) run per-batch NMS and write cols 0..4.
// Both halves depend only on K2 output.
// ---------------------------------------------------------------------------
__global__ __launch_bounds__(256) void fused_out_kernel(
    const float* __restrict__ bbox, const float* __restrict__ kofs,
    const float* __restrict__ kvis, const int* __restrict__ top_idx,
    const float* __restrict__ top_val, float* __restrict__ out)
{
    const int tid = threadIdx.x;

    __shared__ float bx1[NMSK], by1[NMSK], bx2[NMSK], by2[NMSK], area[NMSK];
    __shared__ float sval[NMSK];
    __shared__ unsigned long long sup[NMSK][5];
    __shared__ unsigned long long keepw[5];

    if (blockIdx.x < NBLKE) {
        // ---- elementwise: one thread per output element, cols 5..55 ----
        int t  = blockIdx.x * 256 + tid;          // < BATCH*NMSK*51
        int ci = t % 51;
        int rj = t / 51;
        int j  = rj % NMSK;
        int b  = rj / NMSK;
        int i  = top_idx[b * NMSK + j];
        float stride, cx, cy;
        prior_of(i, stride, cx, cy);
        float v;
        if (ci < 34) {
            float off = kofs[((size_t)b * NANCH + (size_t)i) * 34 + ci];
            v = off * stride + ((ci & 1) ? cy : cx);
        } else {
            float x = kvis[((size_t)b * NANCH + (size_t)i) * KPT + (ci - 34)];
            v = 1.0f / (1.0f + expf(-x));
        }
        out[((size_t)b * NMSK + j) * OUTC + 5 + ci] = v;
        return;
    }

    // ---- per-batch NMS ----
    const int b = blockIdx.x - NBLKE;

    for (int j = tid; j < NMSK; j += 256) {
        int i = top_idx[b * NMSK + j];
        sval[j] = top_val[b * NMSK + j];
        float stride, cx, cy;
        prior_of(i, stride, cx, cy);
        const float* bp = bbox + ((size_t)b * NANCH + (size_t)i) * 4;
        float4 bb = *(const float4*)bp;
        float x = bb.x * stride + cx;
        float y = bb.y * stride + cy;
        float w = expf(bb.z) * stride;
        float h = expf(bb.w) * stride;
        float x1 = x - 0.5f * w, y1 = y - 0.5f * h;
        float x2 = x + 0.5f * w, y2 = y + 0.5f * h;
        bx1[j] = x1; by1[j] = y1; bx2[j] = x2; by2[j] = y2;
        area[j] = fmaxf(x2 - x1, 0.0f) * fmaxf(y2 - y1, 0.0f);
    }
    __syncthreads();

    for (int i = tid; i < NMSK; i += 256) {
        unsigned long long m0 = 0, m1 = 0, m2 = 0, m3 = 0, m4 = 0;
        float ax1 = bx1[i], ay1 = by1[i], ax2 = bx2[i], ay2 = by2[i], aa = area[i];
        for (int j = i + 1; j < NMSK; ++j) {
            float lx = fmaxf(ax1, bx1[j]);
            float ly = fmaxf(ay1, by1[j]);
            float rx = fminf(ax2, bx2[j]);
            float ry = fminf(ay2, by2[j]);
            float iw = fmaxf(rx - lx, 0.0f);
            float ih = fmaxf(ry - ly, 0.0f);
            float inter = iw * ih;
            float iou = inter / (aa + area[j] - inter + 1e-7f);
            if (iou > 0.65f) {
                unsigned long long bit = 1ull << (j & 63);
                switch (j >> 6) {
                    case 0: m0 |= bit; break;
                    case 1: m1 |= bit; break;
                    case 2: m2 |= bit; break;
                    case 3: m3 |= bit; break;
                    default: m4 |= bit; break;
                }
            }
        }
        sup[i][0] = m0; sup[i][1] = m1; sup[i][2] = m2; sup[i][3] = m3; sup[i][4] = m4;
    }
    __syncthreads();

    if (tid < 64) {
        unsigned long long kw;
        if (tid < 4)       kw = ~0ull;
        else if (tid == 4) kw = (1ull << (NMSK - 256)) - 1ull;
        else               kw = 0ull;
        for (int i = 0; i < NMSK; ++i) {
            unsigned int lo = (unsigned int)kw;
            unsigned int hi = (unsigned int)(kw >> 32);
            lo = (unsigned int)__shfl((int)lo, i >> 6, 64);
            hi = (unsigned int)__shfl((int)hi, i >> 6, 64);
            unsigned long long ow = ((unsigned long long)hi << 32) | lo;
            if ((ow >> (i & 63)) & 1ull) {
                if (tid < 5) kw &= ~sup[i][tid];
            }
        }
        if (tid < 5) keepw[tid] = kw;
    }
    __syncthreads();

    // cols 0..4 (box + keep-masked score)
    float* ob = out + (size_t)b * NMSK * OUTC;
    for (int t = tid; t < NMSK * 5; t += 256) {
        int j  = t / 5;
        int ci = t - j * 5;
        float v;
        if (ci == 0)      v = bx1[j];
        else if (ci == 1) v = by1[j];
        else if (ci == 2) v = bx2[j];
        else if (ci == 3) v = by2[j];
        else {
            bool kp = (keepw[j >> 6] >> (j & 63)) & 1ull;
            v = kp ? sval[j] : 0.0f;
        }
        ob[j * OUTC + ci] = v;
    }
}

// ---------------------------------------------------------------------------
extern "C" void kernel_launch(void* const* d_in, const int* in_sizes, int n_in,
                              void* d_out, int out_size, void* d_ws, size_t ws_size,
                              hipStream_t stream) {
    const float* cls  = (const float*)d_in[0];  // [B,N,1]
    const float* bbox = (const float*)d_in[1];  // [B,N,4]
    const float* obj  = (const float*)d_in[2];  // [B,N]
    const float* kofs = (const float*)d_in[3];  // [B,N,17,2]
    const float* kvis = (const float*)d_in[4];  // [B,N,17]
    float* out = (float*)d_out;                 // [B,300,56]

    size_t need_idx = (size_t)BATCH * NMSK * sizeof(int);
    size_t need_val = (size_t)BATCH * NMSK * sizeof(float);
    size_t need_sc  = (size_t)BATCH * NANCH * sizeof(unsigned int);

    int*   top_idx = (int*)d_ws;
    float* top_val = (float*)((char*)d_ws + need_idx);
    unsigned int* sc = (unsigned int*)((char*)d_ws + need_idx + need_val);

    int has_sc = (ws_size >= need_idx + need_val + need_sc) ? 1 : 0;

    if (has_sc) {
        int nblk = (BATCH * NANCH + 255) / 256;
        scores_kernel<<<nblk, 256, 0, stream>>>(cls, obj, sc);
    }
    topk_kernel<<<BATCH, 256, 0, stream>>>(cls, obj, sc, has_sc, top_idx, top_val);
    fused_out_kernel<<<NBLKE + BATCH, 256, 0, stream>>>(bbox, kofs, kvis, top_idx, top_val, out);
}

// Round 4
// 287.498 us; speedup vs baseline: 1.5265x; 1.2151x over previous
//
#include <hip/hip_runtime.h>
#include <math.h>

#define BATCH 128
#define NANCH 8400
#define NMSK  300
#define KPT   17
#define OUTC  56   // 4 box + 1 score + 34 kpt + 17 vis
#define CAND  768  // candidate slots (>=300 + tie margin)
#define NTHR  1024

__device__ __forceinline__ void prior_of(int i, float& stride, float& cx, float& cy) {
    int row, col;
    if (i < 6400)      { stride = 8.0f;  row = i / 80;              col = i - row * 80; }
    else if (i < 8000) { int ii = i - 6400; stride = 16.0f; row = ii / 40; col = ii - row * 40; }
    else               { int ii = i - 8000; stride = 32.0f; row = ii / 20; col = ii - row * 20; }
    cx = ((float)col + 0.5f) * stride;
    cy = ((float)row + 0.5f) * stride;
}

// ---------------------------------------------------------------------------
// K1: all B*N fused scores (np-f32-exact) -> sc bits. Massively parallel.
// DO NOT change this math: bit-exact vs np reference (absmax 0.0 in R2/R3).
// ---------------------------------------------------------------------------
__global__ __launch_bounds__(256) void scores_kernel(
    const float* __restrict__ cls, const float* __restrict__ obj,
    unsigned int* __restrict__ sc)
{
    int i = blockIdx.x * 256 + threadIdx.x;
    if (i < BATCH * NANCH) {
        float ea = (float)exp(-(double)cls[i]);   // correctly-rounded f32 exp == np.exp
        float eo = (float)exp(-(double)obj[i]);
        float sa = 1.0f / (1.0f + ea);
        float so = 1.0f / (1.0f + eo);
        sc[i] = __float_as_uint(sa * so);
    }
}

// ---------------------------------------------------------------------------
// K2: per-batch everything. 128 blocks x 1024 threads.
//   radix-select exact f32 top-300 -> rank order -> box decode -> NMS bitmask
//   -> (wave0: register-replicated greedy scan || waves1-15: kpt/vis writes)
//   -> cols 0..4 write.
// ---------------------------------------------------------------------------
__global__ __launch_bounds__(NTHR) void fused_kernel(
    const float* __restrict__ cls, const float* __restrict__ obj,
    const unsigned int* __restrict__ sc_g, int has_sc,
    const float* __restrict__ bbox, const float* __restrict__ kofs,
    const float* __restrict__ kvis, float* __restrict__ out)
{
    const int b = blockIdx.x;
    const int tid = threadIdx.x;

    __shared__ unsigned int sc[NANCH];
    __shared__ unsigned int hist[256];
    __shared__ unsigned int suf[256];
    __shared__ unsigned int sh_prefix, sh_k, sh_cnt;
    __shared__ unsigned long long ckey[CAND];   // packed (bits<<32)|(~idx)
    __shared__ float bx1[NMSK], by1[NMSK], bx2[NMSK], by2[NMSK], area[NMSK];
    __shared__ float sval[NMSK], pst[NMSK], ppx[NMSK], ppy[NMSK];
    __shared__ int   sidx[NMSK];
    __shared__ unsigned long long supl[NMSK * 6];  // stride 6 for 16B alignment
    __shared__ unsigned long long keepw[5];

    // ---- stage score bits ----
    if (has_sc) {
        const unsigned int* s = sc_g + (size_t)b * NANCH;
        for (int i = tid; i < NANCH; i += NTHR) sc[i] = s[i];
    } else {
        const float* c = cls + (size_t)b * NANCH;
        const float* o = obj + (size_t)b * NANCH;
        for (int i = tid; i < NANCH; i += NTHR) {
            float ea = (float)exp(-(double)c[i]);
            float eo = (float)exp(-(double)o[i]);
            sc[i] = __float_as_uint((1.0f / (1.0f + ea)) * (1.0f / (1.0f + eo)));
        }
    }
    if (tid == 0) { sh_prefix = 0u; sh_k = NMSK; sh_cnt = 0u; }
    __syncthreads();

    // ---- radix-select exact 300th-largest f32 bit pattern ----
    for (int r = 3; r >= 0; --r) {
        if (tid < 256) hist[tid] = 0u;
        __syncthreads();
        unsigned int pfx  = sh_prefix;
        unsigned int kcur = sh_k;
        for (int i = tid; i < NANCH; i += NTHR) {
            unsigned int key = sc[i];
            bool match = (r == 3) || ((key >> ((r + 1) * 8)) == pfx);
            if (match) atomicAdd(&hist[(key >> (r * 8)) & 0xFFu], 1u);
        }
        __syncthreads();
        // wave 0: butterfly suffix-scan of 256 bins (4 bins/lane)
        if (tid < 64) {
            int l = tid;
            unsigned int b0 = hist[4 * l + 0], b1 = hist[4 * l + 1];
            unsigned int b2 = hist[4 * l + 2], b3 = hist[4 * l + 3];
            unsigned int tot = b0 + b1 + b2 + b3;
            unsigned int v = tot;
            #pragma unroll
            for (int d = 1; d < 64; d <<= 1) {
                unsigned int t2 = (unsigned int)__shfl_down((int)v, d, 64);
                if (l + d < 64) v += t2;
            }
            unsigned int above = v - tot;        // sum over lanes > l
            suf[4 * l + 3] = above + b3;
            suf[4 * l + 2] = above + b3 + b2;
            suf[4 * l + 1] = above + b3 + b2 + b1;
            suf[4 * l + 0] = above + tot;
        }
        __syncthreads();
        if (tid < 256) {
            unsigned int ge     = suf[tid];
            unsigned int genext = (tid < 255) ? suf[tid + 1] : 0u;
            if (ge >= kcur && genext < kcur) {   // exactly one thread
                sh_prefix = (pfx << 8) | (unsigned int)tid;
                sh_k      = kcur - genext;
            }
        }
        __syncthreads();
    }

    // ---- compact all keys >= pivot ----
    unsigned int pivot_bits = sh_prefix;
    for (int i = tid; i < NANCH; i += NTHR) {
        unsigned int key = sc[i];
        if (key >= pivot_bits) {
            unsigned int p = atomicAdd(&sh_cnt, 1u);
            if (p < CAND)
                ckey[p] = ((unsigned long long)key << 32)
                        | (unsigned long long)(0xFFFFFFFFu - (unsigned int)i);
        }
    }
    __syncthreads();
    unsigned int M = sh_cnt; if (M > CAND) M = CAND;

    // ---- rank order (score desc, idx asc == lax.top_k); write into LDS ----
    if (tid < (int)M) {
        unsigned long long mine = ckey[tid];
        int rank = 0;
        for (unsigned int t2 = 0; t2 < M; ++t2) rank += (ckey[t2] > mine) ? 1 : 0;
        if (rank < NMSK) {
            sidx[rank] = (int)(0xFFFFFFFFu - (unsigned int)(mine & 0xFFFFFFFFull));
            sval[rank] = __uint_as_float((unsigned int)(mine >> 32));
        }
    }
    __syncthreads();

    // ---- decode the 300 boxes + priors ----
    if (tid < NMSK) {
        int j = tid;
        int i = sidx[j];
        float stride, cx, cy;
        prior_of(i, stride, cx, cy);
        pst[j] = stride; ppx[j] = cx; ppy[j] = cy;
        float4 bb = *(const float4*)(bbox + ((size_t)b * NANCH + (size_t)i) * 4);
        float x = bb.x * stride + cx;
        float y = bb.y * stride + cy;
        float w = expf(bb.z) * stride;
        float h = expf(bb.w) * stride;
        float x1 = x - 0.5f * w, y1 = y - 0.5f * h;
        float x2 = x + 0.5f * w, y2 = y + 0.5f * h;
        bx1[j] = x1; by1[j] = y1; bx2[j] = x2; by2[j] = y2;
        area[j] = fmaxf(x2 - x1, 0.0f) * fmaxf(y2 - y1, 0.0f);
    }
    __syncthreads();

    // ---- suppression bitmask, task = (row i, word w), <=64 inner iters ----
    for (int t = tid; t < NMSK * 5; t += NTHR) {
        int w = t / NMSK;
        int i = t - w * NMSK;
        int jlo = w * 64; if (jlo < i + 1) jlo = i + 1;
        int jhi = w * 64 + 64; if (jhi > NMSK) jhi = NMSK;
        unsigned long long m = 0;
        float ax1 = bx1[i], ay1 = by1[i], ax2 = bx2[i], ay2 = by2[i], aa = area[i];
        for (int j = jlo; j < jhi; ++j) {
            float lx = fmaxf(ax1, bx1[j]);
            float ly = fmaxf(ay1, by1[j]);
            float rx = fminf(ax2, bx2[j]);
            float ry = fminf(ay2, by2[j]);
            float iw = fmaxf(rx - lx, 0.0f);
            float ih = fmaxf(ry - ly, 0.0f);
            float inter = iw * ih;
            float iou = inter / (aa + area[j] - inter + 1e-7f);
            if (iou > 0.65f) m |= 1ull << (j & 63);
        }
        supl[i * 6 + w] = m;
    }
    __syncthreads();

    // ---- wave0: register-replicated greedy scan || others: kpt/vis writes ----
    if (tid < 64) {
        unsigned long long k0 = ~0ull, k1 = ~0ull, k2 = ~0ull, k3 = ~0ull;
        unsigned long long k4 = (1ull << (NMSK - 256)) - 1ull;
        const unsigned long long* sp = supl;
        #define GSTEP(KW, I) \
            if (((KW) >> ((I) & 63)) & 1ull) { \
                const unsigned long long* s = sp + (size_t)(I) * 6; \
                k0 &= ~s[0]; k1 &= ~s[1]; k2 &= ~s[2]; k3 &= ~s[3]; k4 &= ~s[4]; }
        for (int i = 0;   i < 64;   ++i) { GSTEP(k0, i) }
        for (int i = 64;  i < 128;  ++i) { GSTEP(k1, i) }
        for (int i = 128; i < 192;  ++i) { GSTEP(k2, i) }
        for (int i = 192; i < 256;  ++i) { GSTEP(k3, i) }
        for (int i = 256; i < NMSK; ++i) { GSTEP(k4, i) }
        #undef GSTEP
        if (tid == 0) { keepw[0] = k0; keepw[1] = k1; keepw[2] = k2; keepw[3] = k3; keepw[4] = k4; }
    } else {
        // cols 5..55: gathered kpt decode + vis sigmoid
        const float* kof = kofs + (size_t)b * NANCH * 34;
        const float* kvi = kvis + (size_t)b * NANCH * KPT;
        float* ob = out + (size_t)b * NMSK * OUTC;
        for (int e = tid - 64; e < NMSK * 51; e += NTHR - 64) {
            int j  = e / 51;
            int ci = e - j * 51;
            int i  = sidx[j];
            float v;
            if (ci < 34) {
                float off = kof[(size_t)i * 34 + ci];
                v = off * pst[j] + ((ci & 1) ? ppy[j] : ppx[j]);
            } else {
                float x = kvi[(size_t)i * KPT + (ci - 34)];
                v = 1.0f / (1.0f + expf(-x));
            }
            ob[j * OUTC + 5 + ci] = v;
        }
    }
    __syncthreads();

    // ---- cols 0..4 (box + keep-masked score) ----
    float* ob = out + (size_t)b * NMSK * OUTC;
    for (int t = tid; t < NMSK * 5; t += NTHR) {
        int j  = t / 5;
        int ci = t - j * 5;
        float v;
        if (ci == 0)      v = bx1[j];
        else if (ci == 1) v = by1[j];
        else if (ci == 2) v = bx2[j];
        else if (ci == 3) v = by2[j];
        else {
            bool kp = (keepw[j >> 6] >> (j & 63)) & 1ull;
            v = kp ? sval[j] : 0.0f;
        }
        ob[j * OUTC + ci] = v;
    }
}

// ---------------------------------------------------------------------------
extern "C" void kernel_launch(void* const* d_in, const int* in_sizes, int n_in,
                              void* d_out, int out_size, void* d_ws, size_t ws_size,
                              hipStream_t stream) {
    const float* cls  = (const float*)d_in[0];  // [B,N,1]
    const float* bbox = (const float*)d_in[1];  // [B,N,4]
    const float* obj  = (const float*)d_in[2];  // [B,N]
    const float* kofs = (const float*)d_in[3];  // [B,N,17,2]
    const float* kvis = (const float*)d_in[4];  // [B,N,17]
    float* out = (float*)d_out;                 // [B,300,56]

    size_t need_sc = (size_t)BATCH * NANCH * sizeof(unsigned int);
    unsigned int* sc = (unsigned int*)d_ws;
    int has_sc = (ws_size >= need_sc) ? 1 : 0;

    if (has_sc) {
        int nblk = (BATCH * NANCH + 255) / 256;
        scores_kernel<<<nblk, 256, 0, stream>>>(cls, obj, sc);
    }
    fused_kernel<<<BATCH, NTHR, 0, stream>>>(cls, obj, sc, has_sc,
                                             bbox, kofs, kvis, out);
}